// Round 11
// baseline (238.858 us; speedup 1.0000x reference)
//
#include <hip/hip_runtime.h>
#include <hip/hip_bf16.h>

// Flash-attention fwd, causal + key-padding. B=8,S=2048,D=512 fp32 in/out.
// Round 11: register-occupancy attack. M=32 blocks, wave=(q-band, d-half):
// acc 64 + qa 32 regs -> launch_bounds(256,3) -> 12 waves/CU (3 barrier
// groups). d-split QK^T with bf16 S-exchange via LDS; K and V share ONE
// 32KB LDS buffer (V staged after QK^T, flight hidden under softmax).
// m==0 softmax (r9-proven), cohort split on QT=64, parallel merge.

typedef short bf16x8 __attribute__((ext_vector_type(8)));
typedef short s4v    __attribute__((ext_vector_type(4)));
typedef float f32x4  __attribute__((ext_vector_type(4)));
typedef float f4v    __attribute__((ext_vector_type(4)));
typedef float f2v    __attribute__((ext_vector_type(2)));
typedef unsigned int u32;
typedef unsigned short u16;

#define DEVINL __device__ __forceinline__

constexpr int kS = 2048;
constexpr int kD = 512;
constexpr int kB = 8;
constexpr int QT3 = 64;         // q-tiles per batch at M=32
constexpr int KROW = kD + 8;    // legacy-path K row stride
constexpr float kC = 1.4426950408889634f * 0.044194173824159216f; // log2e/sqrt(512)
constexpr size_t kSlot3 = (size_t)32 * kD * 2 + 32 * 4;  // 32,896 B

DEVINL float fast_exp2(float x) {
  float r; asm("v_exp_f32 %0, %1" : "=v"(r) : "v"(x)); return r;
}
DEVINL short f2b(float f) {
  return (short)__builtin_bit_cast(unsigned short, __float2bfloat16(f));
}
DEVINL float b2f(u16 u) { return __builtin_bit_cast(float, (u32)u << 16); }
DEVINL f32x4 mfma16(bf16x8 a, bf16x8 b, f32x4 c) {
  return __builtin_amdgcn_mfma_f32_16x16x32_bf16(a, b, c, 0, 0, 0);
}
DEVINL void gl_lds16(const void* g, void* l) {
  __builtin_amdgcn_global_load_lds(
      (const __attribute__((address_space(1))) u32*)g,
      (__attribute__((address_space(3))) u32*)l, 16, 0, 0);
}
DEVINL float bflo(u32 u) { return __builtin_bit_cast(float, u << 16); }
DEVINL float bfhi(u32 u) { return __builtin_bit_cast(float, u & 0xffff0000u); }

template <int CTRL>
DEVINL float mvdpp(float x) {
  return __builtin_bit_cast(float,
      __builtin_amdgcn_mov_dpp(__builtin_bit_cast(int, x), CTRL, 0xf, 0xf, false));
}
DEVINL float rowsum16(float x) {
  x += mvdpp<0x128>(x);  // row_ror:8
  x += mvdpp<0x124>(x);  // row_ror:4
  x += mvdpp<0x122>(x);  // row_ror:2
  x += mvdpp<0x121>(x);  // row_ror:1
  return x;
}

__host__ __device__ __forceinline__ int nc3(int qt, int TT) {
  return (qt + 1 + TT - 1) / TT;   // tiles = qt+1 at M=32
}

// ------------- fused prologue: K f32->bf16 ; V -> V^T[b][d][s] bf16 --------
__global__ __launch_bounds__(256) void prep(
    const float* __restrict__ K, const float* __restrict__ V,
    short* __restrict__ Kb, short* __restrict__ Vt) {
  __shared__ float Tl[64][65];
  const int blk = blockIdx.x;
  if (blk < 1024) {
    const size_t n4 = (size_t)kB * kS * kD / 4;
    for (size_t i = (size_t)blk * 256 + threadIdx.x; i < n4;
         i += (size_t)1024 * 256) {
      f4v v = *(const f4v*)(K + i * 4);
      s4v o = {f2b(v[0]), f2b(v[1]), f2b(v[2]), f2b(v[3])};
      *(s4v*)(Kb + i * 4) = o;
    }
  } else {
    const int r = blk - 1024;
    const int b = r >> 8, rr = r & 255;
    const int s0 = (rr >> 3) * 64, d0 = (rr & 7) * 64;
    const int t = threadIdx.x;
#pragma unroll
    for (int i = 0; i < 4; ++i) {
      int v = t + i * 256;
      int row = v >> 4, cq = v & 15;
      f4v x = *(const f4v*)(V + ((size_t)(b * kS + s0 + row)) * kD + d0 + cq * 4);
      *(f4v*)&Tl[row][cq * 4] = x;
    }
    __syncthreads();
    const int dd = t >> 2, q = t & 3;
    short out[16];
#pragma unroll
    for (int j = 0; j < 16; ++j) out[j] = f2b(Tl[q * 16 + j][dd]);
    short* dp = Vt + ((size_t)(b * kD + d0 + dd)) * kS + s0 + q * 16;
    *(bf16x8*)dp = *(const bf16x8*)&out[0];
    *(bf16x8*)(dp + 8) = *(const bf16x8*)&out[8];
  }
}

// ---------------- pass 1: M=32, d-split, shared KV buffer ------------------
__global__ __launch_bounds__(256, 3) void attn_p1(
    const float* __restrict__ Qp, const short* __restrict__ Kb,
    const short* __restrict__ Vt, const int* __restrict__ Mp,
    float* __restrict__ Op, char* __restrict__ Part, int TT, int NS) {
  __shared__ __align__(16) short KV[32 * 512];        // 32 KB: K then V
  __shared__ __align__(16) short Plds[32 * 40];       //  2.5 KB
  __shared__ __align__(16) short Slds[2][2][16][32];  //  4 KB bf16 S exchange

  const int tid = threadIdx.x, lane = tid & 63, w = tid >> 6;
  const int qb2 = w & 1, dh = w >> 1;   // wave = (q-band, d-half)
  const int b = blockIdx.x & 7;

  // sub-major cohort decode (all sub=0 chunks first; qt descending within)
  int j = blockIdx.x >> 3, sub = 0, qt = 0;
  for (;;) {
    const int qmin = sub * TT;
    const int cnt = QT3 - qmin;
    if (j < cnt) { qt = (QT3 - 1) - j; break; }
    j -= cnt;
    ++sub;
  }
  const int ntl = qt + 1;
  const int nc = nc3(qt, TT);
  const int t0 = sub * TT, t1 = min(ntl, t0 + TT);
  const int qbase = qt * 32;

  const int l15 = lane & 15, lg = lane >> 4;

  // Q A-frags: rows qbase + qb2*16 + l15, d = dh*256 + k*32 + lg*8, k<8
  bf16x8 qa[8];
  {
    const float* qp =
        Qp + ((size_t)(b * kS) + qbase + qb2 * 16 + l15) * kD + dh * 256 + lg * 8;
#pragma unroll
    for (int k = 0; k < 8; ++k) {
      f4v a = *(const f4v*)(qp + k * 32);
      f4v c = *(const f4v*)(qp + k * 32 + 4);
      bf16x8 q8 = {f2b(a[0]), f2b(a[1]), f2b(a[2]), f2b(a[3]),
                   f2b(c[0]), f2b(c[1]), f2b(c[2]), f2b(c[3])};
      qa[k] = q8;
    }
  }

  f32x4 acc[16];   // O[16q-band][dc*16+l15], dc = dh*16 + 0..15
#pragma unroll
  for (int dc = 0; dc < 16; ++dc) acc[dc] = f32x4{0.f, 0.f, 0.f, 0.f};
  float lsum[4] = {0.f, 0.f, 0.f, 0.f};

  // swizzled K read bases (r3-verified; +dh*256 shorts selects the d-half)
  const int kx4 = (l15 >> 2) & 1;
  const short* kbase2 = &KV[l15 * 512 + dh * 256 + ((lg ^ (l15 & 3)) << 3)];
  const short* kpE = kbase2 + (kx4 << 5);
  const short* kpO = kbase2 - (kx4 << 5);
  // swizzled V read bases (r9/r10-verified superrow layout)
  const int vcom = (l15 >> 2) * 128 + ((l15 >> 1) & 1) * 64 + ((lg ^ (l15 >> 2)) << 3);
  const short* vE = &KV[vcom + (l15 & 1) * 32];
  const short* vO = &KV[vcom + ((l15 & 1) ^ 1) * 32];

  const short* kbG = Kb + (size_t)(b * kS) * kD;
  const short* vtG = Vt + (size_t)(b * kD) * kS;
  const int* mp = Mp + (size_t)b * kS;

  for (int t = t0; t < t1; ++t) {
    const int kv0 = t * 32;

    __builtin_amdgcn_s_barrier();   // B0: prev PV done reading KV + P
    __builtin_amdgcn_sched_barrier(0);

    // ---- stage K tile into KV (8 gl_lds/wave) ----
    {
      const short* kb = kbG + (size_t)kv0 * kD;
#pragma unroll
      for (int r8 = 0; r8 < 8; ++r8) {
        const int row = w * 8 + r8;
        gl_lds16(kb + (size_t)row * kD + ((lane ^ (row & 7)) << 3),
                 &KV[row * 512]);
      }
    }
    asm volatile("s_waitcnt vmcnt(0)" ::: "memory");
    __builtin_amdgcn_s_barrier();   // B1: K ready
    __builtin_amdgcn_sched_barrier(0);

    // ---- QK^T partial over this wave's 256-d half ----
    f32x4 sA = {0.f,0.f,0.f,0.f}, sB = {0.f,0.f,0.f,0.f};
    f32x4 sC = {0.f,0.f,0.f,0.f}, sD = {0.f,0.f,0.f,0.f};
    __builtin_amdgcn_s_setprio(1);
#pragma unroll
    for (int k = 0; k < 8; k += 2) {
      const short* pa = kpE + (k << 5);
      const short* pb = kpO + ((k + 1) << 5);
      bf16x8 b00 = *(const bf16x8*)(pa);
      bf16x8 b10 = *(const bf16x8*)(pa + 16 * 512);
      bf16x8 b01 = *(const bf16x8*)(pb);
      bf16x8 b11 = *(const bf16x8*)(pb + 16 * 512);
      sA = mfma16(qa[k], b00, sA);
      sB = mfma16(qa[k], b10, sB);
      sC = mfma16(qa[k + 1], b01, sC);
      sD = mfma16(qa[k + 1], b11, sD);
    }
    __builtin_amdgcn_s_setprio(0);
    f32x4 s0p = sA + sC;  // kv col kv0+l15,    band rows lg*4+j
    f32x4 s1p = sB + sD;  // kv col kv0+16+l15

    // ---- publish own half (bf16) ----
#pragma unroll
    for (int jx = 0; jx < 4; ++jx) {
      Slds[qb2][dh][lg * 4 + jx][l15]      = f2b(s0p[jx]);
      Slds[qb2][dh][lg * 4 + jx][l15 + 16] = f2b(s1p[jx]);
    }
    asm volatile("s_waitcnt lgkmcnt(0)" ::: "memory");
    __builtin_amdgcn_s_barrier();   // B2: K reads done + S halves visible
    __builtin_amdgcn_sched_barrier(0);

    // ---- stage V into the SAME buffer (safe after B2); flight hidden below
    {
      const short* vt = vtG + kv0;
      const int li = lane & 15, lh = lane >> 4;
#pragma unroll
      for (int r8 = 0; r8 < 8; ++r8) {
        const int i = w * 8 + r8;
        const int sr = 4 * i + lh;
        const int logical = li ^ (4 * (i & 1) + lh);
        const int d = sr * 4 + (logical >> 2);
        gl_lds16(vt + (size_t)d * kS + ((logical & 3) << 3), &KV[i * 512]);
      }
    }

    // ---- softmax (sum halves, mask, exp2, rowsum) while V is in flight ----
    {
      const int kvg0 = kv0 + l15, kvg1 = kvg0 + 16;
      const int mk0 = mp[kvg0], mk1 = mp[kvg1];
      const int qrow0 = qbase + qb2 * 16 + lg * 4;
#pragma unroll
      for (int jx = 0; jx < 4; ++jx) {
        const int row = lg * 4 + jx;
        const float o0 = b2f((u16)Slds[qb2][dh ^ 1][row][l15]);
        const float o1 = b2f((u16)Slds[qb2][dh ^ 1][row][l15 + 16]);
        float x0 = s0p[jx] + o0;
        float x1 = s1p[jx] + o1;
        const int q = qrow0 + jx;
        x0 = (kvg0 <= q && mk0 != 0) ? x0 : -1e30f;
        x1 = (kvg1 <= q && mk1 != 0) ? x1 : -1e30f;
        const float p0 = fast_exp2(x0 * kC);
        const float p1 = fast_exp2(x1 * kC);
        lsum[jx] += rowsum16(p0 + p1);
        if (dh == 0) {
          Plds[(qb2 * 16 + row) * 40 + l15]      = f2b(p0);
          Plds[(qb2 * 16 + row) * 40 + 16 + l15] = f2b(p1);
        }
      }
    }
    asm volatile("s_waitcnt vmcnt(0) lgkmcnt(0)" ::: "memory");
    __builtin_amdgcn_s_barrier();   // B3: V ready + P visible
    __builtin_amdgcn_sched_barrier(0);

    // ---- PV: wave covers band qb2 x d-half dh (16 dc chunks) ----
    bf16x8 pa = *(const bf16x8*)&Plds[(qb2 * 16 + l15) * 40 + lg * 8];
    __builtin_amdgcn_s_setprio(1);
#pragma unroll
    for (int dc2 = 0; dc2 < 16; dc2 += 2) {
      const int dcA = dh * 16 + dc2;
      bf16x8 vf0 = *(const bf16x8*)(vE + dcA * 512);
      bf16x8 vf1 = *(const bf16x8*)(vO + (dcA + 1) * 512);
      acc[dc2]     = mfma16(pa, vf0, acc[dc2]);
      acc[dc2 + 1] = mfma16(pa, vf1, acc[dc2 + 1]);
    }
    __builtin_amdgcn_s_setprio(0);
  }

  // ---- epilogue ----
  if (nc == 1) {
#pragma unroll
    for (int jx = 0; jx < 4; ++jx) {
      const float inv = __builtin_amdgcn_rcpf(lsum[jx]);
      const int row = qbase + qb2 * 16 + lg * 4 + jx;
      float* op = Op + ((size_t)(b * kS) + row) * kD + dh * 256 + l15;
#pragma unroll
      for (int dc = 0; dc < 16; ++dc) op[dc * 16] = acc[dc][jx] * inv;
    }
  } else {
    int sb = 0;
    for (int q = 0; q < qt; ++q) {
      int n2 = nc3(q, TT);
      if (n2 > 1) sb += n2;
    }
    char* sp = Part + ((size_t)b * NS + sb + sub) * kSlot3;
    short* po = (short*)sp;
    float* pm = (float*)(sp + (size_t)32 * kD * 2);
#pragma unroll
    for (int jx = 0; jx < 4; ++jx) {
      const int row = qb2 * 16 + lg * 4 + jx;
#pragma unroll
      for (int dc = 0; dc < 16; ++dc)
        po[row * kD + dh * 256 + dc * 16 + l15] = f2b(acc[dc][jx]);
      if (dh == 0 && l15 == 0) pm[row] = lsum[jx];
    }
  }
}

// ---------------- pass 2: merge chunk partials (plain sums) ----------------
__global__ __launch_bounds__(256) void attn_p2(const char* __restrict__ Part,
                                               float* __restrict__ Op,
                                               int TT, int NS) {
  const int bid = blockIdx.x;
  const int b = bid & 7, rg = (bid >> 3) & 3, idx = bid >> 5;
  int seen = 0, qt = 0, nc = 0, sbase = 0, sb = 0;
  for (int q = 0; q < QT3; ++q) {
    int n2 = nc3(q, TT);
    if (n2 > 1) {
      if (seen == idx) { qt = q; nc = n2; sbase = sb; break; }
      seen++;
      sb += n2;
    }
  }
  const int t = threadIdx.x;
  const char* base = Part + ((size_t)b * NS + sbase) * kSlot3;
  const int r0 = rg * 8;
  for (int row = r0; row < r0 + 8; ++row) {
    float lt = 0.f;
    for (int c = 0; c < nc; ++c)
      lt += *(const float*)(base + c * kSlot3 + 32768 + row * 4);
    const float inv = 1.0f / lt;
    float a0 = 0.f, a1 = 0.f;
    for (int c = 0; c < nc; ++c) {
      u32 u = *(const u32*)(base + c * kSlot3 + ((size_t)row * kD + t * 2) * 2);
      a0 += bflo(u);
      a1 += bfhi(u);
    }
    f2v o = {a0 * inv, a1 * inv};
    *(f2v*)(Op + ((size_t)(b * kS) + qt * 32 + row) * kD + t * 2) = o;
  }
}

// ---------------- legacy fallback (round-1 kernel, f32 direct) -------------
__global__ __launch_bounds__(256) void attn_legacy(
    const float* __restrict__ Qp, const float* __restrict__ Kp,
    const float* __restrict__ Vp, const int* __restrict__ Mp,
    float* __restrict__ Op) {
  __shared__ __align__(16) short Klds[32 * KROW];
  __shared__ __align__(16) short Vlds[32 * kD];
  __shared__ __align__(16) short Plds[4 * 16 * 40];
  __shared__ int Mlds[kS];
  const int tid = threadIdx.x, lane = tid & 63, w = tid >> 6;
  const int bb = blockIdx.x & 7, qt = blockIdx.x >> 3, qb = qt * 64;
  for (int i = tid; i < kS; i += 256) Mlds[i] = Mp[(size_t)bb * kS + i];
  const int l15 = lane & 15, lg = lane >> 4;
  bf16x8 qa[16];
  {
    const float* qp = Qp + ((size_t)bb * kS + qb + w * 16 + l15) * kD + lg * 8;
#pragma unroll
    for (int k = 0; k < 16; ++k) {
      f4v a = *(const f4v*)(qp + k * 32);
      f4v c = *(const f4v*)(qp + k * 32 + 4);
      bf16x8 q8 = {f2b(a[0]), f2b(a[1]), f2b(a[2]), f2b(a[3]),
                   f2b(c[0]), f2b(c[1]), f2b(c[2]), f2b(c[3])};
      qa[k] = q8;
    }
  }
  f32x4 acc[32];
#pragma unroll
  for (int dc = 0; dc < 32; ++dc) acc[dc] = f32x4{0.f, 0.f, 0.f, 0.f};
  float mrow[4] = {-1e30f, -1e30f, -1e30f, -1e30f};
  float lsum[4] = {0.f, 0.f, 0.f, 0.f};
  short* Pl = &Plds[w * 16 * 40];
  const int vphys = ((lg ^ ((lane >> 2) & 3)) * 16);
  const int nt = 2 * qt + 2;
  for (int t = 0; t < nt; ++t) {
    const int kv0 = t * 32;
    __syncthreads();
    {
      const int r = tid >> 3, dg = tid & 7;
      const float* src = Kp + ((size_t)bb * kS + kv0 + r) * kD + dg * 64;
      short* dst = &Klds[r * KROW + dg * 64];
#pragma unroll
      for (int i = 0; i < 16; ++i) {
        f4v v = *(const f4v*)(src + i * 4);
        s4v s = {f2b(v[0]), f2b(v[1]), f2b(v[2]), f2b(v[3])};
        *(s4v*)(dst + i * 4) = s;
      }
    }
    {
      const int kvq = tid & 7, dqi = tid >> 3;
      const float* vbase = Vp + ((size_t)bb * kS + kv0 + kvq * 4) * kD;
#pragma unroll
      for (int it = 0; it < 4; ++it) {
        const int dq = dqi + 32 * it;
        f4v v0 = *(const f4v*)(vbase + 0 * kD + dq * 4);
        f4v v1 = *(const f4v*)(vbase + 1 * kD + dq * 4);
        f4v v2 = *(const f4v*)(vbase + 2 * kD + dq * 4);
        f4v v3 = *(const f4v*)(vbase + 3 * kD + dq * 4);
        const int pch = (((kvq >> 1) ^ (dq & 3)) * 16) + (kvq & 1) * 8;
#pragma unroll
        for (int c = 0; c < 4; ++c) {
          s4v s = {f2b(v0[c]), f2b(v1[c]), f2b(v2[c]), f2b(v3[c])};
          *(s4v*)((char*)Vlds + (dq * 4 + c) * 64 + pch) = s;
        }
      }
    }
    __syncthreads();
    f32x4 sA = {0.f,0.f,0.f,0.f}, sB = {0.f,0.f,0.f,0.f};
    f32x4 sC = {0.f,0.f,0.f,0.f}, sD = {0.f,0.f,0.f,0.f};
    const short* krow0 = &Klds[l15 * KROW + lg * 8];
    const short* krow1 = krow0 + 16 * KROW;
#pragma unroll
    for (int k = 0; k < 16; k += 2) {
      bf16x8 b00 = *(const bf16x8*)(krow0 + k * 32);
      bf16x8 b10 = *(const bf16x8*)(krow1 + k * 32);
      bf16x8 b01 = *(const bf16x8*)(krow0 + (k + 1) * 32);
      bf16x8 b11 = *(const bf16x8*)(krow1 + (k + 1) * 32);
      sA = mfma16(qa[k], b00, sA);
      sB = mfma16(qa[k], b10, sB);
      sC = mfma16(qa[k + 1], b01, sC);
      sD = mfma16(qa[k + 1], b11, sD);
    }
    f32x4 s0 = sA + sC, s1 = sB + sD;
    const int kvg0 = kv0 + l15, kvg1 = kvg0 + 16;
    const int mk0 = Mlds[kvg0], mk1 = Mlds[kvg1];
    const int qrow0 = qb + w * 16 + lg * 4;
    float rm[4];
#pragma unroll
    for (int jx = 0; jx < 4; ++jx) {
      const int q = qrow0 + jx;
      float x0 = (kvg0 <= q && mk0 != 0) ? s0[jx] : -1e30f;
      float x1 = (kvg1 <= q && mk1 != 0) ? s1[jx] : -1e30f;
      s0[jx] = x0; s1[jx] = x1;
      rm[jx] = fmaxf(x0, x1);
    }
#pragma unroll
    for (int sh = 1; sh <= 8; sh <<= 1) {
#pragma unroll
      for (int jx = 0; jx < 4; ++jx) rm[jx] = fmaxf(rm[jx], __shfl_xor(rm[jx], sh));
    }
    bool need = false;
#pragma unroll
    for (int jx = 0; jx < 4; ++jx) need |= ((rm[jx] - mrow[jx]) * kC > 8.0f);
    if (__any(need)) {
#pragma unroll
      for (int jx = 0; jx < 4; ++jx) {
        float mn = fmaxf(mrow[jx], rm[jx]);
        float corr = fast_exp2((mrow[jx] - mn) * kC);
        mrow[jx] = mn;
        lsum[jx] *= corr;
#pragma unroll
        for (int dc = 0; dc < 32; ++dc) acc[dc][jx] *= corr;
      }
    }
    float ts[4];
#pragma unroll
    for (int jx = 0; jx < 4; ++jx) {
      float p0 = fast_exp2((s0[jx] - mrow[jx]) * kC);
      float p1 = fast_exp2((s1[jx] - mrow[jx]) * kC);
      ts[jx] = p0 + p1;
      Pl[(lg * 4 + jx) * 40 + l15]      = f2b(p0);
      Pl[(lg * 4 + jx) * 40 + 16 + l15] = f2b(p1);
    }
#pragma unroll
    for (int sh = 1; sh <= 8; sh <<= 1) {
#pragma unroll
      for (int jx = 0; jx < 4; ++jx) ts[jx] += __shfl_xor(ts[jx], sh);
    }
#pragma unroll
    for (int jx = 0; jx < 4; ++jx) lsum[jx] += ts[jx];
    bf16x8 pf = *(const bf16x8*)&Pl[l15 * 40 + lg * 8];
#pragma unroll
    for (int dc = 0; dc < 32; ++dc) {
      const bf16x8 vf = *(const bf16x8*)((const char*)Vlds + (dc * 16 + l15) * 64 + vphys);
      acc[dc] = mfma16(pf, vf, acc[dc]);
    }
  }
#pragma unroll
  for (int jx = 0; jx < 4; ++jx) {
    const float inv = __builtin_amdgcn_rcpf(lsum[jx]);
    float* op = Op + ((size_t)bb * kS + qb + w * 16 + lg * 4 + jx) * kD + l15;
#pragma unroll
    for (int dc = 0; dc < 32; ++dc) op[dc * 16] = acc[dc][jx] * inv;
  }
}

extern "C" void kernel_launch(void* const* d_in, const int* in_sizes, int n_in,
                              void* d_out, int out_size, void* d_ws, size_t ws_size,
                              hipStream_t stream) {
  const float* Q = (const float*)d_in[0];
  const float* K = (const float*)d_in[1];
  const float* V = (const float*)d_in[2];
  const int*   M = (const int*)d_in[3];
  float* O = (float*)d_out;

  const size_t tens = (size_t)kB * kS * kD;   // elements per tensor
  const size_t convB = 2 * tens * 2;          // Kb + Vt bytes (33.6 MB)

  if (ws_size < convB) {  // no room: proven round-1 path
    attn_legacy<<<dim3(256), dim3(256), 0, stream>>>(Q, K, V, M, O);
    return;
  }

  short* Kb = (short*)d_ws;
  short* Vt = Kb + tens;
  char* Part = (char*)d_ws + convB;
  const size_t budget = ws_size - convB;

  // pick the most aggressive split whose partials fit the ws budget
  int TT = QT3;  // no-split fallback
  {
    const int cands[4] = {16, 24, 32, 48};
    for (int ci = 0; ci < 4; ++ci) {
      int tt = cands[ci], slots = 0;
      for (int q = 0; q < QT3; ++q) {
        int nc = nc3(q, tt);
        if (nc > 1) slots += nc;
      }
      if ((size_t)kB * slots * kSlot3 <= budget) { TT = tt; break; }
    }
  }
  int NS = 0, NCH = 0, nsplit = 0;
  for (int q = 0; q < QT3; ++q) {
    int nc = nc3(q, TT);
    NCH += nc;
    if (nc > 1) { NS += nc; nsplit++; }
  }

  prep<<<dim3(3072), dim3(256), 0, stream>>>(K, V, Kb, Vt);
  attn_p1<<<dim3(kB * NCH), dim3(256), 0, stream>>>(Q, Kb, Vt, M, O, Part, TT, NS);
  if (nsplit > 0)
    attn_p2<<<dim3(kB * 4 * nsplit), dim3(256), 0, stream>>>(Part, O, TT, NS);
}

// Round 12
// 218.571 us; speedup vs baseline: 1.0928x; 1.0928x over previous
//
#include <hip/hip_runtime.h>
#include <hip/hip_bf16.h>

// Flash-attention fwd, causal + key-padding. B=8,S=2048,D=512 fp32 in/out.
// Round 12: M=64, 4 waves = (qh,dh). d-split QK^T (halves K-reads: each wave
// reads only its 256-d half of K) + f32 S-exchange via LDS; counted-vmcnt
// schedule hides BOTH stage drains (V under QKT+softmax, K(t+1) under
// softmax+PV); 3 barriers/tile; m==0 softmax; d-split PV (r9/r10 verbatim);
// cohort split-KV + parallel merge.

typedef short bf16x8 __attribute__((ext_vector_type(8)));
typedef short s4v    __attribute__((ext_vector_type(4)));
typedef float f32x4  __attribute__((ext_vector_type(4)));
typedef float f4v    __attribute__((ext_vector_type(4)));
typedef float f2v    __attribute__((ext_vector_type(2)));
typedef unsigned int u32;
typedef unsigned short u16;

#define DEVINL __device__ __forceinline__

constexpr int kS = 2048;
constexpr int kD = 512;
constexpr int kB = 8;
constexpr int QT = 32;          // q-tiles per batch at M=64
constexpr int KROW = kD + 8;    // legacy-path K row stride
constexpr float kC = 1.4426950408889634f * 0.044194173824159216f; // log2e/sqrt(512)
constexpr size_t kSlotB = (size_t)64 * kD * 2 + 64 * 4;  // 65,792 B (O bf16 + l)

DEVINL float fast_exp2(float x) {
  float r; asm("v_exp_f32 %0, %1" : "=v"(r) : "v"(x)); return r;
}
DEVINL short f2b(float f) {
  return (short)__builtin_bit_cast(unsigned short, __float2bfloat16(f));
}
DEVINL f32x4 mfma16(bf16x8 a, bf16x8 b, f32x4 c) {
  return __builtin_amdgcn_mfma_f32_16x16x32_bf16(a, b, c, 0, 0, 0);
}
DEVINL void gl_lds16(const void* g, void* l) {
  __builtin_amdgcn_global_load_lds(
      (const __attribute__((address_space(1))) u32*)g,
      (__attribute__((address_space(3))) u32*)l, 16, 0, 0);
}
DEVINL float bflo(u32 u) { return __builtin_bit_cast(float, u << 16); }
DEVINL float bfhi(u32 u) { return __builtin_bit_cast(float, u & 0xffff0000u); }

template <int CTRL>
DEVINL float mvdpp(float x) {
  return __builtin_bit_cast(float,
      __builtin_amdgcn_mov_dpp(__builtin_bit_cast(int, x), CTRL, 0xf, 0xf, false));
}
DEVINL float rowsum16(float x) {
  x += mvdpp<0x128>(x);  // row_ror:8
  x += mvdpp<0x124>(x);  // row_ror:4
  x += mvdpp<0x122>(x);  // row_ror:2
  x += mvdpp<0x121>(x);  // row_ror:1
  return x;
}

__host__ __device__ __forceinline__ int ncM(int q, int TT) {
  return (2 * q + 2 + TT - 1) / TT;
}

// ------------- fused prologue: K f32->bf16 ; V -> V^T[b][d][s] bf16 --------
__global__ __launch_bounds__(256) void prep(
    const float* __restrict__ K, const float* __restrict__ V,
    short* __restrict__ Kb, short* __restrict__ Vt) {
  __shared__ float Tl[64][65];
  const int blk = blockIdx.x;
  if (blk < 1024) {
    const size_t n4 = (size_t)kB * kS * kD / 4;
    for (size_t i = (size_t)blk * 256 + threadIdx.x; i < n4;
         i += (size_t)1024 * 256) {
      f4v v = *(const f4v*)(K + i * 4);
      s4v o = {f2b(v[0]), f2b(v[1]), f2b(v[2]), f2b(v[3])};
      *(s4v*)(Kb + i * 4) = o;
    }
  } else {
    const int r = blk - 1024;
    const int b = r >> 8, rr = r & 255;
    const int s0 = (rr >> 3) * 64, d0 = (rr & 7) * 64;
    const int t = threadIdx.x;
#pragma unroll
    for (int i = 0; i < 4; ++i) {
      int v = t + i * 256;
      int row = v >> 4, cq = v & 15;
      f4v x = *(const f4v*)(V + ((size_t)(b * kS + s0 + row)) * kD + d0 + cq * 4);
      *(f4v*)&Tl[row][cq * 4] = x;
    }
    __syncthreads();
    const int dd = t >> 2, q = t & 3;
    short out[16];
#pragma unroll
    for (int j = 0; j < 16; ++j) out[j] = f2b(Tl[q * 16 + j][dd]);
    short* dp = Vt + ((size_t)(b * kD + d0 + dd)) * kS + s0 + q * 16;
    *(bf16x8*)dp = *(const bf16x8*)&out[0];
    *(bf16x8*)(dp + 8) = *(const bf16x8*)&out[8];
  }
}

// ------- pass 1: M=64, d-split QK^T + exchange, hidden drains --------------
__global__ __launch_bounds__(256, 2) void attn_p1(
    const float* __restrict__ Qp, const short* __restrict__ Kb,
    const short* __restrict__ Vt, const int* __restrict__ Mp,
    float* __restrict__ Op, char* __restrict__ Part, int TT, int NS) {
  __shared__ __align__(16) short Klds[32 * 512];     // 32,768 B
  __shared__ __align__(16) short Vlds[128 * 128];    // 32,768 B
  __shared__ __align__(16) short Plds[64 * 40];      //  5,120 B
  __shared__ float Slds[2][2][16][33];               //  8,448 B exchange
  __shared__ float Llds[64];                         //    256 B  total 79,360

  const int tid = threadIdx.x, lane = tid & 63, w = tid >> 6;
  const int qh = w & 1, dh = w >> 1;
  const int b = blockIdx.x & 7;

  // sub-major cohort decode (all sub=0 chunks first; qt descending within)
  int j = blockIdx.x >> 3, sub = 0, qt = 0;
  for (;;) {
    const int qmin = (sub * TT) >> 1;
    const int cnt = QT - qmin;
    if (j < cnt) { qt = (QT - 1) - j; break; }
    j -= cnt;
    ++sub;
  }
  const int nc = ncM(qt, TT);
  const int ntl = 2 * qt + 2;
  const int t0 = sub * TT, t1 = min(ntl, t0 + TT);
  const int qbase = qt * 64;

  const int l15 = lane & 15, lg = lane >> 4;
  const short* kbG = Kb + (size_t)(b * kS) * kD;
  const short* vtG = Vt + (size_t)(b * kD) * kS;
  const int* mp = Mp + (size_t)b * kS;

  // staging lambdas: 8 gl_lds each; K issued separately from V
  auto stageK = [&](int t) {
    const short* kb = kbG + (size_t)(t * 32) * kD;
#pragma unroll
    for (int r8 = 0; r8 < 8; ++r8) {
      const int row = w * 8 + r8;
      gl_lds16(kb + (size_t)row * kD + ((lane ^ (row & 7)) << 3),
               &Klds[row * 512]);
    }
  };
  auto stageV = [&](int t) {
    const short* vt = vtG + t * 32;
    const int li = lane & 15, lh = lane >> 4;
#pragma unroll
    for (int r8 = 0; r8 < 8; ++r8) {
      const int i = w * 8 + r8;
      const int sr = 4 * i + lh;
      const int logical = li ^ (4 * (i & 1) + lh);
      const int d = sr * 4 + (logical >> 2);
      gl_lds16(vt + (size_t)d * kS + ((logical & 3) << 3), &Vlds[i * 512]);
    }
  };

  stageK(t0);  // prologue: K(t0) in flight

  // Q A-frags: rows qbase + qh*32 + qrb*16 + l15, d = dh*256 + k*32 + lg*8
  bf16x8 qa[2][8];
  {
#pragma unroll
    for (int qrb = 0; qrb < 2; ++qrb) {
      const float* qp = Qp +
          ((size_t)(b * kS) + qbase + qh * 32 + qrb * 16 + l15) * kD +
          dh * 256 + lg * 8;
#pragma unroll
      for (int k = 0; k < 8; ++k) {
        f4v a = *(const f4v*)(qp + k * 32);
        f4v c = *(const f4v*)(qp + k * 32 + 4);
        bf16x8 q8 = {f2b(a[0]), f2b(a[1]), f2b(a[2]), f2b(a[3]),
                     f2b(c[0]), f2b(c[1]), f2b(c[2]), f2b(c[3])};
        qa[qrb][k] = q8;
      }
    }
  }

  // d-split PV accumulator (wave w = d-quarter): acc[qb][db]
  f32x4 acc[4][8];
#pragma unroll
  for (int qb = 0; qb < 4; ++qb)
#pragma unroll
    for (int db = 0; db < 8; ++db) acc[qb][db] = f32x4{0.f, 0.f, 0.f, 0.f};
  float lsum[4] = {0.f, 0.f, 0.f, 0.f};

  // K swizzled read bases (r3-verified; dh*256 selects d-half)
  const int kx4 = (l15 >> 2) & 1;
  const short* kbase2 = &Klds[l15 * 512 + dh * 256 + ((lg ^ (l15 & 3)) << 3)];
  const short* kpE = kbase2 + (kx4 << 5);
  const short* kpO = kbase2 - (kx4 << 5);
  // V swizzled read bases (r9/r10-verified)
  const int vcom = (l15 >> 2) * 128 + ((l15 >> 1) & 1) * 64 + ((lg ^ (l15 >> 2)) << 3);
  const short* vE = &Vlds[vcom + (l15 & 1) * 32];
  const short* vO = &Vlds[vcom + ((l15 & 1) ^ 1) * 32];

  for (int t = t0; t < t1; ++t) {
    const int kv0 = t * 32;

    // B1: my K(t) done; everyone's PV(t-1) reads done
    asm volatile("s_waitcnt vmcnt(0)" ::: "memory");
    __builtin_amdgcn_s_barrier();
    __builtin_amdgcn_sched_barrier(0);

    stageV(t);  // V(t) drains under QK^T + softmax

    // ---- QK^T partial: S[32q x 32kv] over this wave's 256-d half ----
    f32x4 s00 = {0,0,0,0}, s01 = {0,0,0,0}, s10 = {0,0,0,0}, s11 = {0,0,0,0};
    __builtin_amdgcn_s_setprio(1);
#pragma unroll
    for (int k = 0; k < 8; k += 2) {
      const short* pa = kpE + (k << 5);
      const short* pb = kpO + ((k + 1) << 5);
      bf16x8 b00 = *(const bf16x8*)(pa);             // kvb 0, even k
      bf16x8 b10 = *(const bf16x8*)(pa + 16 * 512);  // kvb 1, even k
      bf16x8 b01 = *(const bf16x8*)(pb);
      bf16x8 b11 = *(const bf16x8*)(pb + 16 * 512);
      s00 = mfma16(qa[0][k], b00, s00);
      s10 = mfma16(qa[1][k], b00, s10);
      s01 = mfma16(qa[0][k], b10, s01);
      s11 = mfma16(qa[1][k], b10, s11);
      s00 = mfma16(qa[0][k + 1], b01, s00);
      s10 = mfma16(qa[1][k + 1], b01, s10);
      s01 = mfma16(qa[0][k + 1], b11, s01);
      s11 = mfma16(qa[1][k + 1], b11, s11);
    }
    __builtin_amdgcn_s_setprio(0);

    // ---- exchange the NON-owned q-row-block (owner qrb == dh) ----
    // region A: partials of qrb=1 (written by dh=0); region B: qrb=0 (by dh=1)
    {
      const f32x4 x0 = (dh == 0) ? s10 : s00;   // kvb 0 of non-owned qrb
      const f32x4 x1 = (dh == 0) ? s11 : s01;   // kvb 1
      const int reg = dh ^ 1;  // dh=0 writes region 1's rows... region idx = dh
#pragma unroll
      for (int jx = 0; jx < 4; ++jx) {
        Slds[dh][qh][lg * 4 + jx][l15]          = x0[jx];
        Slds[dh][qh][lg * 4 + jx][l15 + 16]     = x1[jx];
      }
      (void)reg;
    }
    asm volatile("s_waitcnt lgkmcnt(0)" ::: "memory");
    __builtin_amdgcn_s_barrier();   // B2: exchange visible + K(t) reads done
    __builtin_amdgcn_sched_barrier(0);

    if (t + 1 < t1) stageK(t + 1);  // K(t+1) drains under softmax + PV

    // ---- softmax on owned rows (qrb == dh): add partner partial, mask, exp
    {
      f32x4 o0 = (dh == 0) ? s00 : s10;   // own partial, owned qrb, kvb 0
      f32x4 o1 = (dh == 0) ? s01 : s11;   // kvb 1
      const int kvg0 = kv0 + l15, kvg1 = kvg0 + 16;
      const int mk0 = mp[kvg0], mk1 = mp[kvg1];
      const int qrow0 = qbase + qh * 32 + dh * 16 + lg * 4;
#pragma unroll
      for (int jx = 0; jx < 4; ++jx) {
        // partner's partial for my owned rows lives in region (dh^1)
        const float p0p = Slds[dh ^ 1][qh][lg * 4 + jx][l15];
        const float p1p = Slds[dh ^ 1][qh][lg * 4 + jx][l15 + 16];
        float x0 = o0[jx] + p0p;
        float x1 = o1[jx] + p1p;
        const int q = qrow0 + jx;
        x0 = (kvg0 <= q && mk0 != 0) ? x0 : -1e30f;
        x1 = (kvg1 <= q && mk1 != 0) ? x1 : -1e30f;
        const float p0 = fast_exp2(x0 * kC);
        const float p1 = fast_exp2(x1 * kC);
        lsum[jx] += rowsum16(p0 + p1);
        const int row = qh * 32 + dh * 16 + lg * 4 + jx;
        Plds[row * 40 + l15]      = f2b(p0);
        Plds[row * 40 + 16 + l15] = f2b(p1);
      }
    }
    // wait V(t): outstanding = V(t) [oldest 8] + K(t+1) [8 if issued]
    if (t + 1 < t1) {
      asm volatile("s_waitcnt vmcnt(8) lgkmcnt(0)" ::: "memory");
    } else {
      asm volatile("s_waitcnt vmcnt(0) lgkmcnt(0)" ::: "memory");
    }
    __builtin_amdgcn_s_barrier();   // B3: P visible + V(t) ready
    __builtin_amdgcn_sched_barrier(0);

    // ---- PV, d-split: wave w owns cols [128w, 128w+128) for all 64 rows ----
    __builtin_amdgcn_s_setprio(1);
#pragma unroll
    for (int half = 0; half < 2; ++half) {
      bf16x8 vf[4];
#pragma unroll
      for (int i = 0; i < 4; ++i) {
        const int dc = 8 * w + half * 4 + i;
        vf[i] = (i & 1) ? *(const bf16x8*)(vO + dc * 512)
                        : *(const bf16x8*)(vE + dc * 512);
      }
#pragma unroll
      for (int qb = 0; qb < 4; ++qb) {
        bf16x8 pa = *(const bf16x8*)&Plds[(qb * 16 + l15) * 40 + lg * 8];
#pragma unroll
        for (int i = 0; i < 4; ++i)
          acc[qb][half * 4 + i] = mfma16(pa, vf[i], acc[qb][half * 4 + i]);
      }
    }
    __builtin_amdgcn_s_setprio(0);
    // loop-top B1 of t+1 guards Vlds/Plds overwrite (all PV reads done)
  }

  // ---- publish l, epilogue ----
  __syncthreads();
  if (l15 == 0) {
    f32x4 lv = {lsum[0], lsum[1], lsum[2], lsum[3]};
    *(f32x4*)&Llds[qh * 32 + dh * 16 + lg * 4] = lv;
  }
  __syncthreads();

  if (nc == 1) {
#pragma unroll
    for (int qb = 0; qb < 4; ++qb) {
      f32x4 lv = *(const f32x4*)&Llds[qb * 16 + lg * 4];
#pragma unroll
      for (int jx = 0; jx < 4; ++jx) {
        const float inv = __builtin_amdgcn_rcpf(lv[jx]);
        const int row = qbase + qb * 16 + lg * 4 + jx;
        float* op = Op + ((size_t)(b * kS) + row) * kD + w * 128 + l15;
#pragma unroll
        for (int db = 0; db < 8; ++db) op[db * 16] = acc[qb][db][jx] * inv;
      }
    }
  } else {
    int sb = 0;
    for (int q = 0; q < qt; ++q) {
      int n2 = ncM(q, TT);
      if (n2 > 1) sb += n2;
    }
    char* sp = Part + ((size_t)b * NS + sb + sub) * kSlotB;
    short* po = (short*)sp;
    float* pm = (float*)(sp + (size_t)64 * kD * 2);
#pragma unroll
    for (int qb = 0; qb < 4; ++qb) {
#pragma unroll
      for (int jx = 0; jx < 4; ++jx) {
        const int row = qb * 16 + lg * 4 + jx;
#pragma unroll
        for (int db = 0; db < 8; ++db)
          po[row * kD + w * 128 + db * 16 + l15] = f2b(acc[qb][db][jx]);
      }
    }
    if (l15 == 0) {
#pragma unroll
      for (int jx = 0; jx < 4; ++jx)
        pm[qh * 32 + dh * 16 + lg * 4 + jx] = lsum[jx];
    }
  }
}

// ---------------- pass 2: merge chunk partials (plain sums) ----------------
__global__ __launch_bounds__(256) void attn_p2(const char* __restrict__ Part,
                                               float* __restrict__ Op,
                                               int TT, int NS) {
  const int bid = blockIdx.x;
  const int b = bid & 7, rg = (bid >> 3) & 7, idx = bid >> 6;
  int seen = 0, qt = 0, nc = 0, sbase = 0, sb = 0;
  for (int q = 0; q < QT; ++q) {
    int n2 = ncM(q, TT);
    if (n2 > 1) {
      if (seen == idx) { qt = q; nc = n2; sbase = sb; break; }
      seen++;
      sb += n2;
    }
  }
  const int t = threadIdx.x;
  const char* base = Part + ((size_t)b * NS + sbase) * kSlotB;
  const int r0 = rg * 8;
  for (int row = r0; row < r0 + 8; ++row) {
    float lt = 0.f;
    for (int c = 0; c < nc; ++c)
      lt += *(const float*)(base + c * kSlotB + 65536 + row * 4);
    const float inv = 1.0f / lt;
    float a0 = 0.f, a1 = 0.f;
    for (int c = 0; c < nc; ++c) {
      u32 u = *(const u32*)(base + c * kSlotB + ((size_t)row * kD + t * 2) * 2);
      a0 += bflo(u);
      a1 += bfhi(u);
    }
    f2v o = {a0 * inv, a1 * inv};
    *(f2v*)(Op + ((size_t)(b * kS) + qt * 64 + row) * kD + t * 2) = o;
  }
}

// ---------------- legacy fallback (round-1 kernel, f32 direct) -------------
__global__ __launch_bounds__(256) void attn_legacy(
    const float* __restrict__ Qp, const float* __restrict__ Kp,
    const float* __restrict__ Vp, const int* __restrict__ Mp,
    float* __restrict__ Op) {
  __shared__ __align__(16) short Klds[32 * KROW];
  __shared__ __align__(16) short Vlds[32 * kD];
  __shared__ __align__(16) short Plds[4 * 16 * 40];
  __shared__ int Mlds[kS];
  const int tid = threadIdx.x, lane = tid & 63, w = tid >> 6;
  const int bb = blockIdx.x & 7, qt = blockIdx.x >> 3, qb = qt * 64;
  for (int i = tid; i < kS; i += 256) Mlds[i] = Mp[(size_t)bb * kS + i];
  const int l15 = lane & 15, lg = lane >> 4;
  bf16x8 qa[16];
  {
    const float* qp = Qp + ((size_t)bb * kS + qb + w * 16 + l15) * kD + lg * 8;
#pragma unroll
    for (int k = 0; k < 16; ++k) {
      f4v a = *(const f4v*)(qp + k * 32);
      f4v c = *(const f4v*)(qp + k * 32 + 4);
      bf16x8 q8 = {f2b(a[0]), f2b(a[1]), f2b(a[2]), f2b(a[3]),
                   f2b(c[0]), f2b(c[1]), f2b(c[2]), f2b(c[3])};
      qa[k] = q8;
    }
  }
  f32x4 acc[32];
#pragma unroll
  for (int dc = 0; dc < 32; ++dc) acc[dc] = f32x4{0.f, 0.f, 0.f, 0.f};
  float mrow[4] = {-1e30f, -1e30f, -1e30f, -1e30f};
  float lsum[4] = {0.f, 0.f, 0.f, 0.f};
  short* Pl = &Plds[w * 16 * 40];
  const int vphys = ((lg ^ ((lane >> 2) & 3)) * 16);
  const int nt = 2 * qt + 2;
  for (int t = 0; t < nt; ++t) {
    const int kv0 = t * 32;
    __syncthreads();
    {
      const int r = tid >> 3, dg = tid & 7;
      const float* src = Kp + ((size_t)bb * kS + kv0 + r) * kD + dg * 64;
      short* dst = &Klds[r * KROW + dg * 64];
#pragma unroll
      for (int i = 0; i < 16; ++i) {
        f4v v = *(const f4v*)(src + i * 4);
        s4v s = {f2b(v[0]), f2b(v[1]), f2b(v[2]), f2b(v[3])};
        *(s4v*)(dst + i * 4) = s;
      }
    }
    {
      const int kvq = tid & 7, dqi = tid >> 3;
      const float* vbase = Vp + ((size_t)bb * kS + kv0 + kvq * 4) * kD;
#pragma unroll
      for (int it = 0; it < 4; ++it) {
        const int dq = dqi + 32 * it;
        f4v v0 = *(const f4v*)(vbase + 0 * kD + dq * 4);
        f4v v1 = *(const f4v*)(vbase + 1 * kD + dq * 4);
        f4v v2 = *(const f4v*)(vbase + 2 * kD + dq * 4);
        f4v v3 = *(const f4v*)(vbase + 3 * kD + dq * 4);
        const int pch = (((kvq >> 1) ^ (dq & 3)) * 16) + (kvq & 1) * 8;
#pragma unroll
        for (int c = 0; c < 4; ++c) {
          s4v s = {f2b(v0[c]), f2b(v1[c]), f2b(v2[c]), f2b(v3[c])};
          *(s4v*)((char*)Vlds + (dq * 4 + c) * 64 + pch) = s;
        }
      }
    }
    __syncthreads();
    f32x4 sA = {0.f,0.f,0.f,0.f}, sB = {0.f,0.f,0.f,0.f};
    f32x4 sC = {0.f,0.f,0.f,0.f}, sD = {0.f,0.f,0.f,0.f};
    const short* krow0 = &Klds[l15 * KROW + lg * 8];
    const short* krow1 = krow0 + 16 * KROW;
#pragma unroll
    for (int k = 0; k < 16; k += 2) {
      bf16x8 b00 = *(const bf16x8*)(krow0 + k * 32);
      bf16x8 b10 = *(const bf16x8*)(krow1 + k * 32);
      bf16x8 b01 = *(const bf16x8*)(krow0 + (k + 1) * 32);
      bf16x8 b11 = *(const bf16x8*)(krow1 + (k + 1) * 32);
      sA = mfma16(qa[k], b00, sA);
      sB = mfma16(qa[k], b10, sB);
      sC = mfma16(qa[k + 1], b01, sC);
      sD = mfma16(qa[k + 1], b11, sD);
    }
    f32x4 s0 = sA + sC, s1 = sB + sD;
    const int kvg0 = kv0 + l15, kvg1 = kvg0 + 16;
    const int mk0 = Mlds[kvg0], mk1 = Mlds[kvg1];
    const int qrow0 = qb + w * 16 + lg * 4;
    float rm[4];
#pragma unroll
    for (int jx = 0; jx < 4; ++jx) {
      const int q = qrow0 + jx;
      float x0 = (kvg0 <= q && mk0 != 0) ? s0[jx] : -1e30f;
      float x1 = (kvg1 <= q && mk1 != 0) ? s1[jx] : -1e30f;
      s0[jx] = x0; s1[jx] = x1;
      rm[jx] = fmaxf(x0, x1);
    }
#pragma unroll
    for (int sh = 1; sh <= 8; sh <<= 1) {
#pragma unroll
      for (int jx = 0; jx < 4; ++jx) rm[jx] = fmaxf(rm[jx], __shfl_xor(rm[jx], sh));
    }
    bool need = false;
#pragma unroll
    for (int jx = 0; jx < 4; ++jx) need |= ((rm[jx] - mrow[jx]) * kC > 8.0f);
    if (__any(need)) {
#pragma unroll
      for (int jx = 0; jx < 4; ++jx) {
        float mn = fmaxf(mrow[jx], rm[jx]);
        float corr = fast_exp2((mrow[jx] - mn) * kC);
        mrow[jx] = mn;
        lsum[jx] *= corr;
#pragma unroll
        for (int dc = 0; dc < 32; ++dc) acc[dc][jx] *= corr;
      }
    }
    float ts[4];
#pragma unroll
    for (int jx = 0; jx < 4; ++jx) {
      float p0 = fast_exp2((s0[jx] - mrow[jx]) * kC);
      float p1 = fast_exp2((s1[jx] - mrow[jx]) * kC);
      ts[jx] = p0 + p1;
      Pl[(lg * 4 + jx) * 40 + l15]      = f2b(p0);
      Pl[(lg * 4 + jx) * 40 + 16 + l15] = f2b(p1);
    }
#pragma unroll
    for (int sh = 1; sh <= 8; sh <<= 1) {
#pragma unroll
      for (int jx = 0; jx < 4; ++jx) ts[jx] += __shfl_xor(ts[jx], sh);
    }
#pragma unroll
    for (int jx = 0; jx < 4; ++jx) lsum[jx] += ts[jx];
    bf16x8 pf = *(const bf16x8*)&Pl[l15 * 40 + lg * 8];
#pragma unroll
    for (int dc = 0; dc < 32; ++dc) {
      const bf16x8 vf = *(const bf16x8*)((const char*)Vlds + (dc * 16 + l15) * 64 + vphys);
      acc[dc] = mfma16(pf, vf, acc[dc]);
    }
  }
#pragma unroll
  for (int jx = 0; jx < 4; ++jx) {
    const float inv = __builtin_amdgcn_rcpf(lsum[jx]);
    float* op = Op + ((size_t)bb * kS + qb + w * 16 + lg * 4 + jx) * kD + l15;
#pragma unroll
    for (int dc = 0; dc < 32; ++dc) op[dc * 16] = acc[dc][jx] * inv;
  }
}

extern "C" void kernel_launch(void* const* d_in, const int* in_sizes, int n_in,
                              void* d_out, int out_size, void* d_ws, size_t ws_size,
                              hipStream_t stream) {
  const float* Q = (const float*)d_in[0];
  const float* K = (const float*)d_in[1];
  const float* V = (const float*)d_in[2];
  const int*   M = (const int*)d_in[3];
  float* O = (float*)d_out;

  const size_t tens = (size_t)kB * kS * kD;   // elements per tensor
  const size_t convB = 2 * tens * 2;          // Kb + Vt bytes (33.6 MB)

  if (ws_size < convB) {  // no room: proven round-1 path
    attn_legacy<<<dim3(256), dim3(256), 0, stream>>>(Q, K, V, M, O);
    return;
  }

  short* Kb = (short*)d_ws;
  short* Vt = Kb + tens;
  char* Part = (char*)d_ws + convB;
  const size_t budget = ws_size - convB;

  // most aggressive split whose partials fit ws (TT even for cohort decode)
  int TT = 68;  // no-split fallback
  {
    const int cands[5] = {12, 16, 22, 34, 48};
    for (int ci = 0; ci < 5; ++ci) {
      int tt = cands[ci], slots = 0;
      for (int q = 0; q < QT; ++q) {
        int nc = ncM(q, tt);
        if (nc > 1) slots += nc;
      }
      if ((size_t)kB * slots * kSlotB <= budget) { TT = tt; break; }
    }
  }
  int NS = 0, NCH = 0, nsplit = 0;
  for (int q = 0; q < QT; ++q) {
    int nc = ncM(q, TT);
    NCH += nc;
    if (nc > 1) { NS += nc; nsplit++; }
  }

  prep<<<dim3(3072), dim3(256), 0, stream>>>(K, V, Kb, Vt);
  attn_p1<<<dim3(kB * NCH), dim3(256), 0, stream>>>(Q, Kb, Vt, M, O, Part, TT, NS);
  if (nsplit > 0)
    attn_p2<<<dim3(kB * 8 * nsplit), dim3(256), 0, stream>>>(Part, O, TT, NS);
}